// Round 7
// baseline (225.300 us; speedup 1.0000x reference)
//
#include <hip/hip_runtime.h>

// Problem constants (B,S,D,H,HD) = (4,1024,1024,16,64)
#define B_ 4
#define S_ 1024
#define D_ 1024
#define H_ 16
#define E_ 64
#define BS_ (B_*S_)
#define BHSE_ (B_*H_*S_*E_)   // 4,194,304

typedef __attribute__((ext_vector_type(8))) short bf16x8;   // 8 bf16 in 4 VGPRs
typedef __attribute__((ext_vector_type(4))) float f32x4;
typedef __attribute__((ext_vector_type(4))) unsigned int u32x4;

__device__ __forceinline__ unsigned short f2bf(float f) {
    unsigned int x = __float_as_uint(f);
    x = (x + 0x7FFFu + ((x >> 16) & 1u)) >> 16;   // RNE
    return (unsigned short)x;
}
__device__ __forceinline__ float bf2f(unsigned short u) {
    return __uint_as_float(((unsigned int)u) << 16);
}
__device__ __forceinline__ float ldin(const void* p, size_t i, int isb) {
    return isb ? bf2f(((const unsigned short*)p)[i]) : ((const float*)p)[i];
}

// 2 f32 -> packed 2xbf16 in one VALU op (RNE) — no builtin on gfx950, asm it
__device__ __forceinline__ unsigned int cvtpk(float lo, float hi) {
    unsigned int r;
    asm("v_cvt_pk_bf16_f32 %0, %1, %2" : "=v"(r) : "v"(lo), "v"(hi));
    return r;
}
__device__ __forceinline__ unsigned int bperm(int srclane4, unsigned int v) {
    return (unsigned int)__builtin_amdgcn_ds_bpermute(srclane4, (int)v);
}
__device__ __forceinline__ bf16x8 u4bf(u32x4 w) {
    union { u32x4 u; bf16x8 h; } c; c.u = w; return c.h;
}

// 2^x : v_exp_f32 is natively base-2
#if __has_builtin(__builtin_amdgcn_exp2f)
#define EXP2(x) __builtin_amdgcn_exp2f(x)
#else
#define EXP2(x) __expf((x) * 0.6931471805599453f)
#endif

// async global->LDS, 16B per lane; LDS dest = wave-uniform base + lane*16
__device__ __forceinline__ void gl2lds16(const void* g, void* l) {
    __builtin_amdgcn_global_load_lds(
        (const __attribute__((address_space(1))) void*)g,
        (__attribute__((address_space(3))) void*)l, 16, 0, 0);
}

// ---------------------------------------------------------------------------
// Per-block dtype self-detect. One 64-word coalesced read of q + one wave
// ballot; all waves compute the identical answer. Threshold 48/64.
// ---------------------------------------------------------------------------
__device__ __forceinline__ int detect_isb(const unsigned int* q) {
    unsigned int wv = q[threadIdx.x & 63];
    unsigned int lo = wv & 0xFFFFu;
    unsigned int e = (lo >> 7) & 0xFFu;
    int ok = (lo == 0u) || (e >= 100u && e <= 145u);
    return __popcll(__ballot(ok)) >= 48;
}

// ---------------------------------------------------------------------------
// Kernel 1: merged preprocessing — weights permute, mask bitpack, A convert.
// blocks [0,1024):     W{q,k,v}[h][d][e] -> WT[z][(h*64+e)][d]; Wo[d][o]->WT[3][o][d]
// blocks [1024,5120):  packT[b][kt][s] bit k = mask[b][s][kt*64+k]
// blocks [5120,11264): q,k,v fp32->bf16 one-shot convert (skip if bf16)
// ---------------------------------------------------------------------------
__global__ __launch_bounds__(256) void preproc(
        const void* q_, const void* k_, const void* v_, const int* mask,
        const void* Wq, const void* Wk, const void* Wv, const void* Wo,
        const void* bq_, const void* bk_, const void* bv_, const void* bo_,
        unsigned short* WT, float* biases, unsigned long long* packT,
        unsigned short* Aconv) {
    __shared__ unsigned short Tt[64][72];
    const int isb = detect_isb((const unsigned int*)q_);
    const int blk = blockIdx.x, t = threadIdx.x;

    if (blk < 1024) {
        // ---- weight permute ----
        const int c0 = blk & 15, r0 = ((blk >> 4) & 15) * 64, z = blk >> 8;
        const void* src = (z == 0) ? Wq : (z == 1) ? Wk : (z == 2) ? Wv : Wo;
        {
            int dl = t >> 2, qc = t & 3;
            size_t base;
            if (z < 3) base = (size_t)c0 * 65536 + (size_t)(r0 + dl) * 64 + qc * 16;
            else       base = (size_t)(r0 + dl) * 1024 + (size_t)c0 * 64 + qc * 16;
            if (isb) {
                const unsigned short* s = (const unsigned short*)src + base;
                bf16x8 a0 = *(const bf16x8*)s, a1 = *(const bf16x8*)(s + 8);
#pragma unroll
                for (int j = 0; j < 8; j++) {
                    Tt[qc * 16 + j][dl] = (unsigned short)a0[j];
                    Tt[qc * 16 + 8 + j][dl] = (unsigned short)a1[j];
                }
            } else {
                const float* s = (const float*)src + base;
#pragma unroll
                for (int j = 0; j < 16; j++) Tt[qc * 16 + j][dl] = f2bf(s[j]);
            }
        }
        __syncthreads();
        {
            int el = t >> 2, qc = t & 3;
            size_t dst = (size_t)z * D_ * D_ + (size_t)(c0 * 64 + el) * D_ + r0 + qc * 16;
            *(bf16x8*)&WT[dst]     = *(const bf16x8*)&Tt[el][qc * 16];
            *(bf16x8*)&WT[dst + 8] = *(const bf16x8*)&Tt[el][qc * 16 + 8];
        }
        if (z == 3 && ((blk >> 4) & 15) == 0 && c0 < 4) {
            const void* bs = (c0 == 0) ? bq_ : (c0 == 1) ? bk_
                           : (c0 == 2) ? bv_ : bo_;
#pragma unroll
            for (int j = 0; j < 4; j++) {
                int i = t * 4 + j;
                biases[c0 * 1024 + i] = ldin(bs, i, isb);
            }
        }
    } else if (blk < 5120) {
        // ---- mask bitpack: unit = (b, kt, 4 s-rows) per wave ----
        int unit = (blk - 1024) * 4 + (t >> 6);
        int lane = t & 63;
        int b = unit >> 12, rem = unit & 4095, s0 = (rem >> 4) * 4, kt = rem & 15;
        const int* mb = mask + ((size_t)b * 1024 + s0) * 1024 + kt * 64 + lane;
        unsigned long long bits[4];
#pragma unroll
        for (int j = 0; j < 4; j++) bits[j] = __ballot(mb[j * 1024] != 0);
        if (lane < 4) {
            unsigned long long bb = (lane == 0) ? bits[0] : (lane == 1) ? bits[1]
                                  : (lane == 2) ? bits[2] : bits[3];
            packT[((size_t)b * 16 + kt) * 1024 + s0 + lane] = bb;
        }
    } else {
        // ---- q,k,v fp32 -> bf16 ----
        if (isb) return;
        int blk2 = blk - 5120;
        const int z = blk2 >> 11;
        const float* s = (z == 0) ? (const float*)q_ : (z == 1) ? (const float*)k_
                                                                : (const float*)v_;
        const size_t i = ((size_t)(blk2 & 2047) * 256 + t) * 8;
        f32x4 a0 = *(const f32x4*)(s + i);
        f32x4 a1 = *(const f32x4*)(s + i + 4);
        bf16x8 o;
#pragma unroll
        for (int j = 0; j < 4; j++) {
            o[j]     = (short)f2bf(a0[j]);
            o[4 + j] = (short)f2bf(a1[j]);
        }
        *(bf16x8*)&Aconv[(size_t)z * ((size_t)BS_ * D_) + i] = o;
    }
}

// ---------------------------------------------------------------------------
// Kernel 3: bf16 MFMA GEMM (DMA dbuf, one barrier/iter, XOR-4 swizzle).
// MODE 0: proj, 128x128 tiles, grid (32,8,3), XCD m-stripes.
// MODE 1: final GEMM, 128x64 tiles, grid (32,16), XCD m-stripes.
// (unchanged from R12)
// ---------------------------------------------------------------------------
template<int BM, int BN, int MODE, int MINW>
__global__ __launch_bounds__(256, MINW) void gemm_k(
        const void* A0, const void* A1, const void* A2, const unsigned short* Aconv,
        const unsigned short* BtB, const float* biasB, void* dstB,
        const unsigned int* qdet) {
    constexpr int TOT16 = (BM + BN) * 32;       // ushorts per buffer
    constexpr int CALLS = TOT16 / 512;          // 1KB chunks (16 rows x 32 cols)
    constexpr int CPW = CALLS / 4;
    constexpr int MT = BM / 32;                 // wave-tile (BM/2)x(BN/2)
    constexpr int NT = BN / 32;
    __shared__ unsigned short buf[2][TOT16];

    const int fl = detect_isb(qdet);
    const int t = threadIdx.x, lane = t & 63, w = t >> 6;
    const int lm = lane & 15, q4 = lane >> 4;
    const int wm = w >> 1, wn = w & 1;
    const int lr = lane >> 2;                    // row-in-chunk 0..15
    const int ls = lane & 3;                     // LDS slot 0..3
    const int lg = ls ^ ((lr >> 1) & 3);         // source granule (swizzle)

    const unsigned short* Abf;
    const unsigned short* Bt;
    const float* bias;
    int z = 0, m0, n0, phase;
    if (MODE == 0) {
        // grid (32,8,3); dispatch id -> XCD = id & 7 (round-robin)
        int bid = blockIdx.x + gridDim.x * (blockIdx.y + gridDim.y * blockIdx.z);
        int xcd = bid & 7, idx = bid >> 3;       // idx 0..95 within XCD
        z = idx >> 5;                            // 0..2 (sequential per XCD)
        int r = idx & 31;
        int mt = (xcd << 2) + (r & 3);           // XCD x owns m-tiles 4x..4x+3
        int nt = r >> 2;                         // 0..7
        m0 = mt * BM; n0 = nt * BN;
        phase = (nt * 13 + z * 5) & 31;          // same-B blocks K-aligned
        const void* Ain = (z == 0) ? A0 : (z == 1 ? A1 : A2);
        Abf = fl ? (const unsigned short*)Ain
                 : Aconv + (size_t)z * ((size_t)BS_ * D_);
        Bt = BtB + (size_t)z * D_ * D_;
        bias = biasB + z * 1024;
    } else {
        Abf = (const unsigned short*)A0;         // heads, always bf16
        Bt = BtB; bias = biasB;
        // grid (32,16): 512 blocks; xcd owns m-tiles [4x,4x+4) x all 16 nt
        int bid = blockIdx.x + (blockIdx.y << 5);
        int xcd = bid & 7, idx = bid >> 3;       // idx 0..63
        m0 = ((xcd << 2) + (idx & 3)) * BM;
        n0 = (idx >> 2) * BN;
        phase = ((idx >> 2) * 13) & 31;
    }

    // stage K-slice kk into buffer bi (swizzled: slot s of row r holds
    // global granule s ^ ((r>>1)&3)) — pure DMA, A and B both bf16
    auto stage = [&](int kk, int bi) {
#pragma unroll
        for (int i = 0; i < CPW; ++i) {
            int c = w * CPW + i;
            int row = c * 16 + lr;
            const unsigned short* g;
            if (row < BM)
                g = Abf + (size_t)(m0 + row) * D_ + kk + lg * 8;
            else
                g = Bt + (size_t)(n0 + row - BM) * D_ + kk + lg * 8;
            gl2lds16(g, &buf[bi][c * 512]);
        }
    };

    f32x4 acc[MT][NT];
#pragma unroll
    for (int i = 0; i < MT; i++)
#pragma unroll
        for (int j = 0; j < NT; j++) acc[i][j] = (f32x4){0.f, 0.f, 0.f, 0.f};

    stage((phase & 31) * 32, 0);
    for (int it = 0; it < D_ / 32; ++it) {
        const int bi = it & 1;
        __syncthreads();                 // drains the prefetch of slice `it`
        if (it < D_ / 32 - 1) stage(((it + 1 + phase) & 31) * 32, bi ^ 1);

        const unsigned short* As = buf[bi];
        const unsigned short* Bs = buf[bi] + BM * 32;
        bf16x8 af[MT], bv[NT];
#pragma unroll
        for (int mt = 0; mt < MT; mt++) {
            int row = wm * (BM / 2) + mt * 16 + lm;
            af[mt] = *(const bf16x8*)&As[row * 32 + (q4 ^ ((row >> 1) & 3)) * 8];
        }
#pragma unroll
        for (int nt = 0; nt < NT; nt++) {
            int row = wn * (BN / 2) + nt * 16 + lm;
            bv[nt] = *(const bf16x8*)&Bs[row * 32 + (q4 ^ ((row >> 1) & 3)) * 8];
        }
#pragma unroll
        for (int mt = 0; mt < MT; mt++)
#pragma unroll
            for (int nt = 0; nt < NT; nt++)
                acc[mt][nt] = __builtin_amdgcn_mfma_f32_16x16x32_bf16(
                    af[mt], bv[nt], acc[mt][nt], 0, 0, 0);
    }

    // epilogue: C/D layout col=lane&15, row=(lane>>4)*4+reg
#pragma unroll
    for (int mt = 0; mt < MT; mt++)
#pragma unroll
        for (int nt = 0; nt < NT; nt++) {
            int N = n0 + wn * (BN / 2) + nt * 16 + lm;
            int Mb = m0 + wm * (BM / 2) + mt * 16 + q4 * 4;
            if (MODE == 0 && z == 2) {
                // V^T: 4 consecutive s per lane -> one b64 store
                int bb = Mb >> 10, sb = Mb & 1023, hh = N >> 6, e = N & 63;
                unsigned long long hv = 0;
#pragma unroll
                for (int r = 0; r < 4; r++)
                    hv |= (unsigned long long)f2bf(acc[mt][nt][r] + bias[N]) << (16 * r);
                unsigned short* d16 = (unsigned short*)dstB + (size_t)2 * BHSE_;
                *(unsigned long long*)&d16[(((size_t)(bb * H_ + hh) * E_ + e) << 10) + sb] = hv;
            } else {
#pragma unroll
                for (int r = 0; r < 4; r++) {
                    int M = Mb + r;
                    float v = acc[mt][nt][r] + bias[N];
                    if (MODE == 0) {
                        int bb = M >> 10, s = M & 1023, hh = N >> 6, e = N & 63;
                        unsigned short* d16 = (unsigned short*)dstB + (size_t)z * BHSE_;
                        d16[((size_t)(bb * H_ + hh) * S_ + s) * E_ + e] = f2bf(v);
                    } else {
                        size_t idx = (size_t)M * D_ + N;
                        if (fl) ((unsigned short*)dstB)[idx] = f2bf(v);
                        else    ((float*)dstB)[idx] = v;
                    }
                }
            }
        }
}

// ---------------------------------------------------------------------------
// Kernel 4 (R15): fused attention. CHANGED vs R14:
//  (1) QBLK 128 -> 256: 1024 threads / 16 waves, grid = 4 qt x 64 hb = 256
//      blocks = exactly 1/CU (zero tail). K/V staged 4x per head instead of
//      8x -> per-CU L2 staging traffic halves again. Waves/CU unchanged
//      (16 = 4/SIMD); per-wave structure identical; 32 DMA chunks over 16
//      waves = 2 issues/wave/tile.
//  (2) partial-max threshold check: the defer-max branch only needs SOME
//      lane over THR; every score is in some lane's partial max, so check
//      __all on the per-lane partial max (no shfls). Full row-max reduction
//      (2x shfl_xor) moved INSIDE the rarely-taken branch; mrun stays
//      row-uniform (only updated in-branch with the true row max).
// ---------------------------------------------------------------------------
__global__ __launch_bounds__(1024, 4) void attn64(
        const unsigned short* Qp, const unsigned short* Kp, const unsigned short* VpT,
        const unsigned long long* packT, unsigned short* heads) {
    __shared__ unsigned short KT[2][8192];   // [buf][128 keys x 64 e], swizzled
    __shared__ unsigned short VT[2][8192];   // [buf][2 sub][64 e x 64 keys], swz

    // XCD remap: grid (4,16,4): bid = qt + 4*(h + 16*b); hw xcd = bid&7.
    // Give each xcd 8 full hb's: hb = xcd*8 + (idx&7), qt = idx>>3 (0..3).
    const int bid = blockIdx.x + (blockIdx.y << 2) + (blockIdx.z << 6);
    const int xcd = bid & 7, idx = bid >> 3;
    const int qt = idx >> 3;
    const int hb = xcd * 8 + (idx & 7);
    const int h = hb & 15, b = hb >> 4;

    const int t = threadIdx.x, w = t >> 6, lane = t & 63, lm = lane & 15, q4 = lane >> 4;
    const size_t bh = ((size_t)b * H_ + h) * S_ * E_;
    const unsigned short* Qb = Qp + bh;
    const unsigned short* Kb = Kp + bh;
    const unsigned short* Vb = VpT + bh;                // Vb[e*1024 + s]
    const int q0 = qt * 256 + w * 16;

    // per-lane invariant DMA source offsets (ushort units)
    const int l3 = lane >> 3, l7 = lane & 7;
    const int kLaneOff = l3 * 64 + (l7 ^ l3) * 8;       // within an 8-row K chunk
    const int vLaneOff = l3 * 1024 + (l7 ^ l3) * 8;     // within an 8-row V chunk

    // swizzled LDS fragment chunk indices (granule = 8 ushorts)
    const int sw = lm & 7;
    const int c0 = (q4 ^ sw) * 8, c1 = ((q4 ^ 4) ^ sw) * 8;

    // bpermute source byte-addresses for the P redistribution
    const int srcA4 = ((lane & 15) | ((lane & 16) << 1)) << 2;  // (lm+(q4&1)*32)*4
    const int srcB4 = srcA4 + 64;                               // +16 lanes
    const bool selHi = (lane & 32) != 0;                        // q4 >= 2

    // Q B-fragments, held for the whole sweep
    bf16x8 bq0 = *(const bf16x8*)&Qb[(size_t)(q0 + lm) * E_ + q4 * 8];
    bf16x8 bq1 = *(const bf16x8*)&Qb[(size_t)(q0 + lm) * E_ + 32 + q4 * 8];

    // all-ones A-fragment for the denominator MFMA
    bf16x8 ones;
#pragma unroll
    for (int j = 0; j < 8; j++) ones[j] = (short)0x3F80;

    f32x4 oacc[4];
#pragma unroll
    for (int i = 0; i < 4; i++) oacc[i] = (f32x4){0.f, 0.f, 0.f, 0.f};
    f32x4 accL = (f32x4){0.f, 0.f, 0.f, 0.f};
    float mrun = -3.0e38f;
    const float scale2 = 0.03125f * 1.4426950408889634f;   // log2e / sqrt(D)

// 128-key tile = 32 x 1KB chunks over 16 waves: 2 DMA issues/wave/tile.
// K chunks 0..15: rows c*8..c*8+7 of [128 keys][64 e].
// V chunks 16..31: cc=c-16, sub=cc>>3, ec=cc&7 -> e-rows ec*8.., keys sub*64..
#define STAGE(tile, bufi)                                                     \
    {                                                                         \
        int k0s = (tile) * 128;                                               \
        _Pragma("unroll")                                                     \
        for (int i_ = 0; i_ < 2; ++i_) {                                      \
            int c_ = w * 2 + i_;                                              \
            if (c_ < 16) {                                                    \
                gl2lds16(Kb + (size_t)k0s * 64 + c_ * 512 + kLaneOff,         \
                         &KT[bufi][c_ * 512]);                                \
            } else {                                                          \
                int cc_ = c_ - 16, sub_ = cc_ >> 3, ec_ = cc_ & 7;            \
                gl2lds16(Vb + (size_t)ec_ * 8192 + k0s + sub_ * 64 + vLaneOff,\
                         &VT[bufi][sub_ * 4096 + ec_ * 512]);                 \
            }                                                                 \
        }                                                                     \
    }

    STAGE(0, 0)
    unsigned long long mk0 = packT[(size_t)b * 16 * 1024 + q0 + lm];
    unsigned long long mk1 = packT[((size_t)b * 16 + 1) * 1024 + q0 + lm];

    for (int T = 0; T < S_ / 128; ++T) {
        const int bufi = T & 1;
        __syncthreads();                 // own-vmcnt drain + barrier: tile T ready
        unsigned long long mkn0 = 0, mkn1 = 0;
        if (T < 7) {
            STAGE(T + 1, bufi ^ 1)
            mkn0 = packT[((size_t)b * 16 + 2 * T + 2) * 1024 + q0 + lm];
            mkn1 = packT[((size_t)b * 16 + 2 * T + 3) * 1024 + q0 + lm];
        }

        // Sc^T for both 64-key sub-tiles (16 MFMAs)
        f32x4 st[2][4];
#pragma unroll
        for (int sub = 0; sub < 2; ++sub)
#pragma unroll
            for (int jt = 0; jt < 4; ++jt) {
                const unsigned short* kr = &KT[bufi][(sub * 64 + jt * 16 + lm) * 64];
                bf16x8 ka0 = *(const bf16x8*)&kr[c0];
                bf16x8 ka1 = *(const bf16x8*)&kr[c1];
                f32x4 zz = (f32x4){0.f, 0.f, 0.f, 0.f};
                zz = __builtin_amdgcn_mfma_f32_16x16x32_bf16(ka0, bq0, zz, 0, 0, 0);
                zz = __builtin_amdgcn_mfma_f32_16x16x32_bf16(ka1, bq1, zz, 0, 0, 0);
                st[sub][jt] = zz;
            }

        // per-lane PARTIAL row max over this lane's 32 raw scores (masked
        // entries included: harmless overestimate)
        float tmx = -3.0e38f;
#pragma unroll
        for (int sub = 0; sub < 2; ++sub)
#pragma unroll
            for (int jt = 0; jt < 4; ++jt) {
                float a = fmaxf(st[sub][jt][0], st[sub][jt][1]);
                float c = fmaxf(st[sub][jt][2], st[sub][jt][3]);
                tmx = fmaxf(tmx, fmaxf(a, c));
            }
        float pmax = tmx * scale2;       // per-lane partial scaled tile max

        // defer-max: every score is in some lane's partial max, so __all on
        // the partials covers all (q,k). Full row-max only inside the branch.
        if (!__all(pmax - mrun <= 8.f)) {
            float rmx = pmax;
            rmx = fmaxf(rmx, __shfl_xor(rmx, 16, 64));
            rmx = fmaxf(rmx, __shfl_xor(rmx, 32, 64));   // true row max
            float mnew = fmaxf(mrun, rmx);
            float alpha = EXP2(mrun - mnew);
            accL = accL * alpha;
#pragma unroll
            for (int nt = 0; nt < 4; nt++) oacc[nt] = oacc[nt] * alpha;
            mrun = mnew;
        }
        const float mneg = -mrun;

        // exp + mask + pack, both subs
        unsigned int cl[2][8];
#pragma unroll
        for (int sub = 0; sub < 2; ++sub) {
            unsigned long long mk = sub ? mk1 : mk0;
            unsigned int mn = (unsigned int)(mk >> (q4 * 4));
            unsigned int mh = (unsigned int)(mk >> (q4 * 4 + 32));
#pragma unroll
            for (int jt = 0; jt < 4; ++jt) {
                unsigned int mm = (jt & 2) ? mh : mn;
                const int sh = (jt & 1) * 16;
                float p0 = EXP2(fmaf(st[sub][jt][0], scale2, mneg));
                float p1 = EXP2(fmaf(st[sub][jt][1], scale2, mneg));
                float p2 = EXP2(fmaf(st[sub][jt][2], scale2, mneg));
                float p3 = EXP2(fmaf(st[sub][jt][3], scale2, mneg));
                p0 = (mm & (1u << (sh + 0))) ? p0 : 0.f;
                p1 = (mm & (1u << (sh + 1))) ? p1 : 0.f;
                p2 = (mm & (1u << (sh + 2))) ? p2 : 0.f;
                p3 = (mm & (1u << (sh + 3))) ? p3 : 0.f;
                cl[sub][jt * 2]     = cvtpk(p0, p1);
                cl[sub][jt * 2 + 1] = cvtpk(p2, p3);
            }
        }

        // in-register C->B redistribution per sub, then denom + PV MFMAs
#pragma unroll
        for (int sub = 0; sub < 2; ++sub) {
            unsigned int* c = cl[sub];
            u32x4 w0, w1;
            {
                unsigned int aA0 = bperm(srcA4, c[0]), aA2 = bperm(srcA4, c[2]);
                unsigned int aA1 = bperm(srcA4, c[1]), aA3 = bperm(srcA4, c[3]);
                unsigned int aB0 = bperm(srcB4, c[0]), aB2 = bperm(srcB4, c[2]);
                unsigned int aB1 = bperm(srcB4, c[1]), aB3 = bperm(srcB4, c[3]);
                w0 = (u32x4){selHi ? aA2 : aA0, selHi ? aA3 : aA1,
                             selHi ? aB2 : aB0, selHi ? aB3 : aB1};
                unsigned int bA0 = bperm(srcA4, c[4]), bA2 = bperm(srcA4, c[6]);
                unsigned int bA1 = bperm(srcA4, c[5]), bA3 = bperm(srcA4, c[7]);
                unsigned int bB0 = bperm(srcB4, c[4]), bB2 = bperm(srcB4, c[6]);
                unsigned int bB1 = bperm(srcB4, c[5]), bB3 = bperm(srcB4, c[7]);
                w1 = (u32x4){selHi ? bA2 : bA0, selHi ? bA3 : bA1,
                             selHi ? bB2 : bB0, selHi ? bB3 : bB1};
            }
            bf16x8 bp0 = u4bf(w0);
            bf16x8 bp1 = u4bf(w1);

            // denominator via ones-MFMA (rows of D = col-sums of B)
            accL = __builtin_amdgcn_mfma_f32_16x16x32_bf16(ones, bp0, accL, 0, 0, 0);
            accL = __builtin_amdgcn_mfma_f32_16x16x32_bf16(ones, bp1, accL, 0, 0, 0);

            // PV from this sub's V block
            const unsigned short* vbase = &VT[bufi][sub * 4096];
#pragma unroll
            for (int nt = 0; nt < 4; nt++) {
                const unsigned short* vr = &vbase[(nt * 16 + lm) * 64];
                bf16x8 va0 = *(const bf16x8*)&vr[c0];
                bf16x8 va1 = *(const bf16x8*)&vr[c1];
                oacc[nt] = __builtin_amdgcn_mfma_f32_16x16x32_bf16(va0, bp0, oacc[nt], 0, 0, 0);
                oacc[nt] = __builtin_amdgcn_mfma_f32_16x16x32_bf16(va1, bp1, oacc[nt], 0, 0, 0);
            }
        }

        mk0 = mkn0; mk1 = mkn1;
    }

    float inv = 1.0f / accL[0];
#pragma unroll
    for (int nt = 0; nt < 4; nt++) {
        unsigned int lo = cvtpk(oacc[nt][0] * inv, oacc[nt][1] * inv);
        unsigned int hi = cvtpk(oacc[nt][2] * inv, oacc[nt][3] * inv);
        unsigned long long hv = (unsigned long long)lo | ((unsigned long long)hi << 32);
        *(unsigned long long*)&heads[(size_t)(b * S_ + q0 + lm) * D_ + h * E_ + nt * 16 + q4 * 4] = hv;
    }
}

// ---------------------------------------------------------------------------
extern "C" void kernel_launch(void* const* d_in, const int* in_sizes, int n_in,
                              void* d_out, int out_size, void* d_ws, size_t ws_size,
                              hipStream_t stream) {
    char* ws = (char*)d_ws;
    unsigned short* WT = (unsigned short*)(ws + 256);    // [4][1024][1024] bf16
    unsigned short* WqT = WT;
    unsigned short* WoT = WT + (size_t)3 * D_ * D_;
    float* biases = (float*)(WT + (size_t)4 * D_ * D_);  // [4][1024]
    float* bq = biases;
    float* bo = biases + 3 * 1024;
    unsigned short* Qp = (unsigned short*)(biases + 4 * 1024);  // [b][h][s][e]
    unsigned short* Kp = Qp + (size_t)BHSE_;                    // [b][h][s][e]
    unsigned short* Vp = Kp + (size_t)BHSE_;                    // [b][h][e][s]
    unsigned short* heads = Vp + (size_t)BHSE_;                 // [b*s][h*64+e]
    unsigned long long* packT = (unsigned long long*)(heads + (size_t)BHSE_);
    unsigned short* Aconv = (unsigned short*)(packT + (size_t)B_ * 16 * S_); // [3][4096][1024] bf16

    // merged preprocessing: weights + bias, mask bitpack, A fp32->bf16
    preproc<<<11264, 256, 0, stream>>>(
        d_in[0], d_in[1], d_in[2], (const int*)d_in[3],
        d_in[4], d_in[6], d_in[8], d_in[10],
        d_in[5], d_in[7], d_in[9], d_in[11],
        WT, biases, packT, Aconv);
    // proj: 128x128 tiles -> 32 x 8 x 3 = 768 blocks (3/CU), XCD m-stripes
    gemm_k<128, 128, 0, 3><<<dim3(32, 8, 3), 256, 0, stream>>>(
        d_in[0], d_in[1], d_in[2], Aconv, WqT, bq, Qp,
        (const unsigned int*)d_in[0]);
    // attn: QBLK=256 x KVBLK=128, 16 waves/block -> 4 x 16 x 4 = 256 blocks
    // (1/CU, zero tail), (h,b)-clustered per XCD
    attn64<<<dim3(4, 16, 4), 1024, 0, stream>>>(Qp, Kp, Vp, packT, heads);
    // final: 128x64 tiles -> 32 x 16 = 512 blocks, XCD m-stripes
    gemm_k<128, 64, 1, 4><<<dim3(32, 16, 1), 256, 0, stream>>>(
        heads, nullptr, nullptr, nullptr, WoT, bo, d_out,
        (const unsigned int*)d_in[0]);
}

// Round 8
// 224.481 us; speedup vs baseline: 1.0036x; 1.0036x over previous
//
#include <hip/hip_runtime.h>

// Problem constants (B,S,D,H,HD) = (4,1024,1024,16,64)
#define B_ 4
#define S_ 1024
#define D_ 1024
#define H_ 16
#define E_ 64
#define BS_ (B_*S_)
#define BHSE_ (B_*H_*S_*E_)   // 4,194,304

typedef __attribute__((ext_vector_type(8))) short bf16x8;   // 8 bf16 in 4 VGPRs
typedef __attribute__((ext_vector_type(4))) float f32x4;
typedef __attribute__((ext_vector_type(4))) unsigned int u32x4;

__device__ __forceinline__ unsigned short f2bf(float f) {
    unsigned int x = __float_as_uint(f);
    x = (x + 0x7FFFu + ((x >> 16) & 1u)) >> 16;   // RNE
    return (unsigned short)x;
}
__device__ __forceinline__ float bf2f(unsigned short u) {
    return __uint_as_float(((unsigned int)u) << 16);
}
__device__ __forceinline__ float ldin(const void* p, size_t i, int isb) {
    return isb ? bf2f(((const unsigned short*)p)[i]) : ((const float*)p)[i];
}

// 2 f32 -> packed 2xbf16 in one VALU op (RNE) — no builtin on gfx950, asm it
__device__ __forceinline__ unsigned int cvtpk(float lo, float hi) {
    unsigned int r;
    asm("v_cvt_pk_bf16_f32 %0, %1, %2" : "=v"(r) : "v"(lo), "v"(hi));
    return r;
}
__device__ __forceinline__ unsigned int bperm(int srclane4, unsigned int v) {
    return (unsigned int)__builtin_amdgcn_ds_bpermute(srclane4, (int)v);
}
__device__ __forceinline__ bf16x8 u4bf(u32x4 w) {
    union { u32x4 u; bf16x8 h; } c; c.u = w; return c.h;
}

// 2^x : v_exp_f32 is natively base-2
#if __has_builtin(__builtin_amdgcn_exp2f)
#define EXP2(x) __builtin_amdgcn_exp2f(x)
#else
#define EXP2(x) __expf((x) * 0.6931471805599453f)
#endif

// async global->LDS, 16B per lane; LDS dest = wave-uniform base + lane*16
__device__ __forceinline__ void gl2lds16(const void* g, void* l) {
    __builtin_amdgcn_global_load_lds(
        (const __attribute__((address_space(1))) void*)g,
        (__attribute__((address_space(3))) void*)l, 16, 0, 0);
}

// ---------------------------------------------------------------------------
// Per-block dtype self-detect. One 64-word coalesced read of q + one wave
// ballot; all waves compute the identical answer. Threshold 48/64.
// ---------------------------------------------------------------------------
__device__ __forceinline__ int detect_isb(const unsigned int* q) {
    unsigned int wv = q[threadIdx.x & 63];
    unsigned int lo = wv & 0xFFFFu;
    unsigned int e = (lo >> 7) & 0xFFu;
    int ok = (lo == 0u) || (e >= 100u && e <= 145u);
    return __popcll(__ballot(ok)) >= 48;
}

// ---------------------------------------------------------------------------
// Kernel 1: merged preprocessing — weights permute, mask bitpack, A convert.
// blocks [0,1024):     W{q,k,v}[h][d][e] -> WT[z][(h*64+e)][d]; Wo[d][o]->WT[3][o][d]
// blocks [1024,5120):  packT[b][kt][s] bit k = mask[b][s][kt*64+k]
// blocks [5120,11264): q,k,v fp32->bf16 one-shot convert (skip if bf16)
// ---------------------------------------------------------------------------
__global__ __launch_bounds__(256) void preproc(
        const void* q_, const void* k_, const void* v_, const int* mask,
        const void* Wq, const void* Wk, const void* Wv, const void* Wo,
        const void* bq_, const void* bk_, const void* bv_, const void* bo_,
        unsigned short* WT, float* biases, unsigned long long* packT,
        unsigned short* Aconv) {
    __shared__ unsigned short Tt[64][72];
    const int isb = detect_isb((const unsigned int*)q_);
    const int blk = blockIdx.x, t = threadIdx.x;

    if (blk < 1024) {
        // ---- weight permute ----
        const int c0 = blk & 15, r0 = ((blk >> 4) & 15) * 64, z = blk >> 8;
        const void* src = (z == 0) ? Wq : (z == 1) ? Wk : (z == 2) ? Wv : Wo;
        {
            int dl = t >> 2, qc = t & 3;
            size_t base;
            if (z < 3) base = (size_t)c0 * 65536 + (size_t)(r0 + dl) * 64 + qc * 16;
            else       base = (size_t)(r0 + dl) * 1024 + (size_t)c0 * 64 + qc * 16;
            if (isb) {
                const unsigned short* s = (const unsigned short*)src + base;
                bf16x8 a0 = *(const bf16x8*)s, a1 = *(const bf16x8*)(s + 8);
#pragma unroll
                for (int j = 0; j < 8; j++) {
                    Tt[qc * 16 + j][dl] = (unsigned short)a0[j];
                    Tt[qc * 16 + 8 + j][dl] = (unsigned short)a1[j];
                }
            } else {
                const float* s = (const float*)src + base;
#pragma unroll
                for (int j = 0; j < 16; j++) Tt[qc * 16 + j][dl] = f2bf(s[j]);
            }
        }
        __syncthreads();
        {
            int el = t >> 2, qc = t & 3;
            size_t dst = (size_t)z * D_ * D_ + (size_t)(c0 * 64 + el) * D_ + r0 + qc * 16;
            *(bf16x8*)&WT[dst]     = *(const bf16x8*)&Tt[el][qc * 16];
            *(bf16x8*)&WT[dst + 8] = *(const bf16x8*)&Tt[el][qc * 16 + 8];
        }
        if (z == 3 && ((blk >> 4) & 15) == 0 && c0 < 4) {
            const void* bs = (c0 == 0) ? bq_ : (c0 == 1) ? bk_
                           : (c0 == 2) ? bv_ : bo_;
#pragma unroll
            for (int j = 0; j < 4; j++) {
                int i = t * 4 + j;
                biases[c0 * 1024 + i] = ldin(bs, i, isb);
            }
        }
    } else if (blk < 5120) {
        // ---- mask bitpack: unit = (b, kt, 4 s-rows) per wave ----
        int unit = (blk - 1024) * 4 + (t >> 6);
        int lane = t & 63;
        int b = unit >> 12, rem = unit & 4095, s0 = (rem >> 4) * 4, kt = rem & 15;
        const int* mb = mask + ((size_t)b * 1024 + s0) * 1024 + kt * 64 + lane;
        unsigned long long bits[4];
#pragma unroll
        for (int j = 0; j < 4; j++) bits[j] = __ballot(mb[j * 1024] != 0);
        if (lane < 4) {
            unsigned long long bb = (lane == 0) ? bits[0] : (lane == 1) ? bits[1]
                                  : (lane == 2) ? bits[2] : bits[3];
            packT[((size_t)b * 16 + kt) * 1024 + s0 + lane] = bb;
        }
    } else {
        // ---- q,k,v fp32 -> bf16 ----
        if (isb) return;
        int blk2 = blk - 5120;
        const int z = blk2 >> 11;
        const float* s = (z == 0) ? (const float*)q_ : (z == 1) ? (const float*)k_
                                                                : (const float*)v_;
        const size_t i = ((size_t)(blk2 & 2047) * 256 + t) * 8;
        f32x4 a0 = *(const f32x4*)(s + i);
        f32x4 a1 = *(const f32x4*)(s + i + 4);
        bf16x8 o;
#pragma unroll
        for (int j = 0; j < 4; j++) {
            o[j]     = (short)f2bf(a0[j]);
            o[4 + j] = (short)f2bf(a1[j]);
        }
        *(bf16x8*)&Aconv[(size_t)z * ((size_t)BS_ * D_) + i] = o;
    }
}

// ---------------------------------------------------------------------------
// Kernel 3 (R16): bf16 MFMA GEMM. CHANGED: counted-vmcnt 2-tiles-ahead
// pipeline (T4). 3 LDS buffers; the per-iter sync is now
//   s_waitcnt vmcnt(CPW)   (own tile-t loads done; t+1/t+2 stay in flight)
//   s_barrier               (all waves' tile-t loads done -> tile t ready)
//   sched_barrier(0)        (pin: no ds_read/DMA crosses the barrier)
// instead of __syncthreads() whose vmcnt(0) drained the prefetch queue and
// exposed full L2/HBM latency every iteration. Race-safety: a wave at the
// barrier has consumed its iter t-1 ds_reads (lgkmcnt before MFMA), so the
// DMA into buffer (t+2)%3 == (t-1)%3 issued after the barrier is safe.
// MODE 0: proj, 128x128 tiles, grid (32,8,3), XCD m-stripes (48KB LDS, 3/CU).
// MODE 1: final GEMM, 128x64 tiles, grid (32,16), XCD m-stripes (36KB, 4/CU).
// ---------------------------------------------------------------------------
template<int BM, int BN, int MODE, int MINW>
__global__ __launch_bounds__(256, MINW) void gemm_k(
        const void* A0, const void* A1, const void* A2, const unsigned short* Aconv,
        const unsigned short* BtB, const float* biasB, void* dstB,
        const unsigned int* qdet) {
    constexpr int TOT16 = (BM + BN) * 32;       // ushorts per buffer
    constexpr int CALLS = TOT16 / 512;          // 1KB chunks (16 rows x 32 cols)
    constexpr int CPW = CALLS / 4;              // DMA issues per wave per tile
    constexpr int MT = BM / 32;                 // wave-tile (BM/2)x(BN/2)
    constexpr int NT = BN / 32;
    __shared__ unsigned short buf[3][TOT16];

    const int fl = detect_isb(qdet);
    const int t = threadIdx.x, lane = t & 63, w = t >> 6;
    const int lm = lane & 15, q4 = lane >> 4;
    const int wm = w >> 1, wn = w & 1;
    const int lr = lane >> 2;                    // row-in-chunk 0..15
    const int ls = lane & 3;                     // LDS slot 0..3
    const int lg = ls ^ ((lr >> 1) & 3);         // source granule (swizzle)

    const unsigned short* Abf;
    const unsigned short* Bt;
    const float* bias;
    int z = 0, m0, n0, phase;
    if (MODE == 0) {
        // grid (32,8,3); dispatch id -> XCD = id & 7 (round-robin)
        int bid = blockIdx.x + gridDim.x * (blockIdx.y + gridDim.y * blockIdx.z);
        int xcd = bid & 7, idx = bid >> 3;       // idx 0..95 within XCD
        z = idx >> 5;                            // 0..2 (sequential per XCD)
        int r = idx & 31;
        int mt = (xcd << 2) + (r & 3);           // XCD x owns m-tiles 4x..4x+3
        int nt = r >> 2;                         // 0..7
        m0 = mt * BM; n0 = nt * BN;
        phase = (nt * 13 + z * 5) & 31;          // same-B blocks K-aligned
        const void* Ain = (z == 0) ? A0 : (z == 1 ? A1 : A2);
        Abf = fl ? (const unsigned short*)Ain
                 : Aconv + (size_t)z * ((size_t)BS_ * D_);
        Bt = BtB + (size_t)z * D_ * D_;
        bias = biasB + z * 1024;
    } else {
        Abf = (const unsigned short*)A0;         // heads, always bf16
        Bt = BtB; bias = biasB;
        // grid (32,16): 512 blocks; xcd owns m-tiles [4x,4x+4) x all 16 nt
        int bid = blockIdx.x + (blockIdx.y << 5);
        int xcd = bid & 7, idx = bid >> 3;       // idx 0..63
        m0 = ((xcd << 2) + (idx & 3)) * BM;
        n0 = (idx >> 2) * BN;
        phase = ((idx >> 2) * 13) & 31;
    }

    // stage K-slice kk into buffer bi (swizzled: slot s of row r holds
    // global granule s ^ ((r>>1)&3)) — pure DMA, A and B both bf16
    auto stage = [&](int kk, int bi) {
#pragma unroll
        for (int i = 0; i < CPW; ++i) {
            int c = w * CPW + i;
            int row = c * 16 + lr;
            const unsigned short* g;
            if (row < BM)
                g = Abf + (size_t)(m0 + row) * D_ + kk + lg * 8;
            else
                g = Bt + (size_t)(n0 + row - BM) * D_ + kk + lg * 8;
            gl2lds16(g, &buf[bi][c * 512]);
        }
    };

    f32x4 acc[MT][NT];
#pragma unroll
    for (int i = 0; i < MT; i++)
#pragma unroll
        for (int j = 0; j < NT; j++) acc[i][j] = (f32x4){0.f, 0.f, 0.f, 0.f};

    // prologue: 2 tiles in flight
    stage((phase & 31) * 32, 0);
    stage(((1 + phase) & 31) * 32, 1);
    for (int it = 0; it < D_ / 32; ++it) {
        const int bi = it % 3;
        // own tile-it loads done; newer tiles stay in flight across barrier
        if (it < D_ / 32 - 1) {
            asm volatile("s_waitcnt vmcnt(%0)" :: "n"(CPW) : "memory");
        } else {
            asm volatile("s_waitcnt vmcnt(0)" ::: "memory");
        }
        __builtin_amdgcn_s_barrier();
        __builtin_amdgcn_sched_barrier(0);
        if (it < D_ / 32 - 2) stage(((it + 2 + phase) & 31) * 32, (it + 2) % 3);

        const unsigned short* As = buf[bi];
        const unsigned short* Bs = buf[bi] + BM * 32;
        bf16x8 af[MT], bv[NT];
#pragma unroll
        for (int mt = 0; mt < MT; mt++) {
            int row = wm * (BM / 2) + mt * 16 + lm;
            af[mt] = *(const bf16x8*)&As[row * 32 + (q4 ^ ((row >> 1) & 3)) * 8];
        }
#pragma unroll
        for (int nt = 0; nt < NT; nt++) {
            int row = wn * (BN / 2) + nt * 16 + lm;
            bv[nt] = *(const bf16x8*)&Bs[row * 32 + (q4 ^ ((row >> 1) & 3)) * 8];
        }
#pragma unroll
        for (int mt = 0; mt < MT; mt++)
#pragma unroll
            for (int nt = 0; nt < NT; nt++)
                acc[mt][nt] = __builtin_amdgcn_mfma_f32_16x16x32_bf16(
                    af[mt], bv[nt], acc[mt][nt], 0, 0, 0);
    }

    // epilogue: C/D layout col=lane&15, row=(lane>>4)*4+reg
#pragma unroll
    for (int mt = 0; mt < MT; mt++)
#pragma unroll
        for (int nt = 0; nt < NT; nt++) {
            int N = n0 + wn * (BN / 2) + nt * 16 + lm;
            int Mb = m0 + wm * (BM / 2) + mt * 16 + q4 * 4;
            if (MODE == 0 && z == 2) {
                // V^T: 4 consecutive s per lane -> one b64 store
                int bb = Mb >> 10, sb = Mb & 1023, hh = N >> 6, e = N & 63;
                unsigned long long hv = 0;
#pragma unroll
                for (int r = 0; r < 4; r++)
                    hv |= (unsigned long long)f2bf(acc[mt][nt][r] + bias[N]) << (16 * r);
                unsigned short* d16 = (unsigned short*)dstB + (size_t)2 * BHSE_;
                *(unsigned long long*)&d16[(((size_t)(bb * H_ + hh) * E_ + e) << 10) + sb] = hv;
            } else {
#pragma unroll
                for (int r = 0; r < 4; r++) {
                    int M = Mb + r;
                    float v = acc[mt][nt][r] + bias[N];
                    if (MODE == 0) {
                        int bb = M >> 10, s = M & 1023, hh = N >> 6, e = N & 63;
                        unsigned short* d16 = (unsigned short*)dstB + (size_t)z * BHSE_;
                        d16[((size_t)(bb * H_ + hh) * S_ + s) * E_ + e] = f2bf(v);
                    } else {
                        size_t idx = (size_t)M * D_ + N;
                        if (fl) ((unsigned short*)dstB)[idx] = f2bf(v);
                        else    ((float*)dstB)[idx] = v;
                    }
                }
            }
        }
}

// ---------------------------------------------------------------------------
// Kernel 4: fused attention — unchanged from R15 (QBLK=256, KVBLK=128,
// 16 waves/block, 256 blocks = 1/CU, (h,b)-clustered per XCD, in-register
// P redistribution, partial-max defer check, ones-MFMA denominator).
// ---------------------------------------------------------------------------
__global__ __launch_bounds__(1024, 4) void attn64(
        const unsigned short* Qp, const unsigned short* Kp, const unsigned short* VpT,
        const unsigned long long* packT, unsigned short* heads) {
    __shared__ unsigned short KT[2][8192];   // [buf][128 keys x 64 e], swizzled
    __shared__ unsigned short VT[2][8192];   // [buf][2 sub][64 e x 64 keys], swz

    // XCD remap: grid (4,16,4): bid = qt + 4*(h + 16*b); hw xcd = bid&7.
    // Give each xcd 8 full hb's: hb = xcd*8 + (idx&7), qt = idx>>3 (0..3).
    const int bid = blockIdx.x + (blockIdx.y << 2) + (blockIdx.z << 6);
    const int xcd = bid & 7, idx = bid >> 3;
    const int qt = idx >> 3;
    const int hb = xcd * 8 + (idx & 7);
    const int h = hb & 15, b = hb >> 4;

    const int t = threadIdx.x, w = t >> 6, lane = t & 63, lm = lane & 15, q4 = lane >> 4;
    const size_t bh = ((size_t)b * H_ + h) * S_ * E_;
    const unsigned short* Qb = Qp + bh;
    const unsigned short* Kb = Kp + bh;
    const unsigned short* Vb = VpT + bh;                // Vb[e*1024 + s]
    const int q0 = qt * 256 + w * 16;

    // per-lane invariant DMA source offsets (ushort units)
    const int l3 = lane >> 3, l7 = lane & 7;
    const int kLaneOff = l3 * 64 + (l7 ^ l3) * 8;       // within an 8-row K chunk
    const int vLaneOff = l3 * 1024 + (l7 ^ l3) * 8;     // within an 8-row V chunk

    // swizzled LDS fragment chunk indices (granule = 8 ushorts)
    const int sw = lm & 7;
    const int c0 = (q4 ^ sw) * 8, c1 = ((q4 ^ 4) ^ sw) * 8;

    // bpermute source byte-addresses for the P redistribution
    const int srcA4 = ((lane & 15) | ((lane & 16) << 1)) << 2;  // (lm+(q4&1)*32)*4
    const int srcB4 = srcA4 + 64;                               // +16 lanes
    const bool selHi = (lane & 32) != 0;                        // q4 >= 2

    // Q B-fragments, held for the whole sweep
    bf16x8 bq0 = *(const bf16x8*)&Qb[(size_t)(q0 + lm) * E_ + q4 * 8];
    bf16x8 bq1 = *(const bf16x8*)&Qb[(size_t)(q0 + lm) * E_ + 32 + q4 * 8];

    // all-ones A-fragment for the denominator MFMA
    bf16x8 ones;
#pragma unroll
    for (int j = 0; j < 8; j++) ones[j] = (short)0x3F80;

    f32x4 oacc[4];
#pragma unroll
    for (int i = 0; i < 4; i++) oacc[i] = (f32x4){0.f, 0.f, 0.f, 0.f};
    f32x4 accL = (f32x4){0.f, 0.f, 0.f, 0.f};
    float mrun = -3.0e38f;
    const float scale2 = 0.03125f * 1.4426950408889634f;   // log2e / sqrt(D)

// 128-key tile = 32 x 1KB chunks over 16 waves: 2 DMA issues/wave/tile.
// K chunks 0..15: rows c*8..c*8+7 of [128 keys][64 e].
// V chunks 16..31: cc=c-16, sub=cc>>3, ec=cc&7 -> e-rows ec*8.., keys sub*64..
#define STAGE(tile, bufi)                                                     \
    {                                                                         \
        int k0s = (tile) * 128;                                               \
        _Pragma("unroll")                                                     \
        for (int i_ = 0; i_ < 2; ++i_) {                                      \
            int c_ = w * 2 + i_;                                              \
            if (c_ < 16) {                                                    \
                gl2lds16(Kb + (size_t)k0s * 64 + c_ * 512 + kLaneOff,         \
                         &KT[bufi][c_ * 512]);                                \
            } else {                                                          \
                int cc_ = c_ - 16, sub_ = cc_ >> 3, ec_ = cc_ & 7;            \
                gl2lds16(Vb + (size_t)ec_ * 8192 + k0s + sub_ * 64 + vLaneOff,\
                         &VT[bufi][sub_ * 4096 + ec_ * 512]);                 \
            }                                                                 \
        }                                                                     \
    }

    STAGE(0, 0)
    unsigned long long mk0 = packT[(size_t)b * 16 * 1024 + q0 + lm];
    unsigned long long mk1 = packT[((size_t)b * 16 + 1) * 1024 + q0 + lm];

    for (int T = 0; T < S_ / 128; ++T) {
        const int bufi = T & 1;
        __syncthreads();                 // own-vmcnt drain + barrier: tile T ready
        unsigned long long mkn0 = 0, mkn1 = 0;
        if (T < 7) {
            STAGE(T + 1, bufi ^ 1)
            mkn0 = packT[((size_t)b * 16 + 2 * T + 2) * 1024 + q0 + lm];
            mkn1 = packT[((size_t)b * 16 + 2 * T + 3) * 1024 + q0 + lm];
        }

        // Sc^T for both 64-key sub-tiles (16 MFMAs)
        f32x4 st[2][4];
#pragma unroll
        for (int sub = 0; sub < 2; ++sub)
#pragma unroll
            for (int jt = 0; jt < 4; ++jt) {
                const unsigned short* kr = &KT[bufi][(sub * 64 + jt * 16 + lm) * 64];
                bf16x8 ka0 = *(const bf16x8*)&kr[c0];
                bf16x8 ka1 = *(const bf16x8*)&kr[c1];
                f32x4 zz = (f32x4){0.f, 0.f, 0.f, 0.f};
                zz = __builtin_amdgcn_mfma_f32_16x16x32_bf16(ka0, bq0, zz, 0, 0, 0);
                zz = __builtin_amdgcn_mfma_f32_16x16x32_bf16(ka1, bq1, zz, 0, 0, 0);
                st[sub][jt] = zz;
            }

        // per-lane PARTIAL row max over this lane's 32 raw scores (masked
        // entries included: harmless overestimate)
        float tmx = -3.0e38f;
#pragma unroll
        for (int sub = 0; sub < 2; ++sub)
#pragma unroll
            for (int jt = 0; jt < 4; ++jt) {
                float a = fmaxf(st[sub][jt][0], st[sub][jt][1]);
                float c = fmaxf(st[sub][jt][2], st[sub][jt][3]);
                tmx = fmaxf(tmx, fmaxf(a, c));
            }
        float pmax = tmx * scale2;       // per-lane partial scaled tile max

        // defer-max: every score is in some lane's partial max, so __all on
        // the partials covers all (q,k). Full row-max only inside the branch.
        if (!__all(pmax - mrun <= 8.f)) {
            float rmx = pmax;
            rmx = fmaxf(rmx, __shfl_xor(rmx, 16, 64));
            rmx = fmaxf(rmx, __shfl_xor(rmx, 32, 64));   // true row max
            float mnew = fmaxf(mrun, rmx);
            float alpha = EXP2(mrun - mnew);
            accL = accL * alpha;
#pragma unroll
            for (int nt = 0; nt < 4; nt++) oacc[nt] = oacc[nt] * alpha;
            mrun = mnew;
        }
        const float mneg = -mrun;

        // exp + mask + pack, both subs
        unsigned int cl[2][8];
#pragma unroll
        for (int sub = 0; sub < 2; ++sub) {
            unsigned long long mk = sub ? mk1 : mk0;
            unsigned int mn = (unsigned int)(mk >> (q4 * 4));
            unsigned int mh = (unsigned int)(mk >> (q4 * 4 + 32));
#pragma unroll
            for (int jt = 0; jt < 4; ++jt) {
                unsigned int mm = (jt & 2) ? mh : mn;
                const int sh = (jt & 1) * 16;
                float p0 = EXP2(fmaf(st[sub][jt][0], scale2, mneg));
                float p1 = EXP2(fmaf(st[sub][jt][1], scale2, mneg));
                float p2 = EXP2(fmaf(st[sub][jt][2], scale2, mneg));
                float p3 = EXP2(fmaf(st[sub][jt][3], scale2, mneg));
                p0 = (mm & (1u << (sh + 0))) ? p0 : 0.f;
                p1 = (mm & (1u << (sh + 1))) ? p1 : 0.f;
                p2 = (mm & (1u << (sh + 2))) ? p2 : 0.f;
                p3 = (mm & (1u << (sh + 3))) ? p3 : 0.f;
                cl[sub][jt * 2]     = cvtpk(p0, p1);
                cl[sub][jt * 2 + 1] = cvtpk(p2, p3);
            }
        }

        // in-register C->B redistribution per sub, then denom + PV MFMAs
#pragma unroll
        for (int sub = 0; sub < 2; ++sub) {
            unsigned int* c = cl[sub];
            u32x4 w0, w1;
            {
                unsigned int aA0 = bperm(srcA4, c[0]), aA2 = bperm(srcA4, c[2]);
                unsigned int aA1 = bperm(srcA4, c[1]), aA3 = bperm(srcA4, c[3]);
                unsigned int aB0 = bperm(srcB4, c[0]), aB2 = bperm(srcB4, c[2]);
                unsigned int aB1 = bperm(srcB4, c[1]), aB3 = bperm(srcB4, c[3]);
                w0 = (u32x4){selHi ? aA2 : aA0, selHi ? aA3 : aA1,
                             selHi ? aB2 : aB0, selHi ? aB3 : aB1};
                unsigned int bA0 = bperm(srcA4, c[4]), bA2 = bperm(srcA4, c[6]);
                unsigned int bA1 = bperm(srcA4, c[5]), bA3 = bperm(srcA4, c[7]);
                unsigned int bB0 = bperm(srcB4, c[4]), bB2 = bperm(srcB4, c[6]);
                unsigned int bB1 = bperm(srcB4, c[5]), bB3 = bperm(srcB4, c[7]);
                w1 = (u32x4){selHi ? bA2 : bA0, selHi ? bA3 : bA1,
                             selHi ? bB2 : bB0, selHi ? bB3 : bB1};
            }
            bf16x8 bp0 = u4bf(w0);
            bf16x8 bp1 = u4bf(w1);

            // denominator via ones-MFMA (rows of D = col-sums of B)
            accL = __builtin_amdgcn_mfma_f32_16x16x32_bf16(ones, bp0, accL, 0, 0, 0);
            accL = __builtin_amdgcn_mfma_f32_16x16x32_bf16(ones, bp1, accL, 0, 0, 0);

            // PV from this sub's V block
            const unsigned short* vbase = &VT[bufi][sub * 4096];
#pragma unroll
            for (int nt = 0; nt < 4; nt++) {
                const unsigned short* vr = &vbase[(nt * 16 + lm) * 64];
                bf16x8 va0 = *(const bf16x8*)&vr[c0];
                bf16x8 va1 = *(const bf16x8*)&vr[c1];
                oacc[nt] = __builtin_amdgcn_mfma_f32_16x16x32_bf16(va0, bp0, oacc[nt], 0, 0, 0);
                oacc[nt] = __builtin_amdgcn_mfma_f32_16x16x32_bf16(va1, bp1, oacc[nt], 0, 0, 0);
            }
        }

        mk0 = mkn0; mk1 = mkn1;
    }

    float inv = 1.0f / accL[0];
#pragma unroll
    for (int nt = 0; nt < 4; nt++) {
        unsigned int lo = cvtpk(oacc[nt][0] * inv, oacc[nt][1] * inv);
        unsigned int hi = cvtpk(oacc[nt][2] * inv, oacc[nt][3] * inv);
        unsigned long long hv = (unsigned long long)lo | ((unsigned long long)hi << 32);
        *(unsigned long long*)&heads[(size_t)(b * S_ + q0 + lm) * D_ + h * E_ + nt * 16 + q4 * 4] = hv;
    }
}

// ---------------------------------------------------------------------------
extern "C" void kernel_launch(void* const* d_in, const int* in_sizes, int n_in,
                              void* d_out, int out_size, void* d_ws, size_t ws_size,
                              hipStream_t stream) {
    char* ws = (char*)d_ws;
    unsigned short* WT = (unsigned short*)(ws + 256);    // [4][1024][1024] bf16
    unsigned short* WqT = WT;
    unsigned short* WoT = WT + (size_t)3 * D_ * D_;
    float* biases = (float*)(WT + (size_t)4 * D_ * D_);  // [4][1024]
    float* bq = biases;
    float* bo = biases + 3 * 1024;
    unsigned short* Qp = (unsigned short*)(biases + 4 * 1024);  // [b][h][s][e]
    unsigned short* Kp = Qp + (size_t)BHSE_;                    // [b][h][s][e]
    unsigned short* Vp = Kp + (size_t)BHSE_;                    // [b][h][e][s]
    unsigned short* heads = Vp + (size_t)BHSE_;                 // [b*s][h*64+e]
    unsigned long long* packT = (unsigned long long*)(heads + (size_t)BHSE_);
    unsigned short* Aconv = (unsigned short*)(packT + (size_t)B_ * 16 * S_); // [3][4096][1024] bf16

    // merged preprocessing: weights + bias, mask bitpack, A fp32->bf16
    preproc<<<11264, 256, 0, stream>>>(
        d_in[0], d_in[1], d_in[2], (const int*)d_in[3],
        d_in[4], d_in[6], d_in[8], d_in[10],
        d_in[5], d_in[7], d_in[9], d_in[11],
        WT, biases, packT, Aconv);
    // proj: 128x128 tiles -> 32 x 8 x 3 = 768 blocks (3/CU), XCD m-stripes,
    // counted-vmcnt 2-deep pipeline
    gemm_k<128, 128, 0, 3><<<dim3(32, 8, 3), 256, 0, stream>>>(
        d_in[0], d_in[1], d_in[2], Aconv, WqT, bq, Qp,
        (const unsigned int*)d_in[0]);
    // attn: QBLK=256 x KVBLK=128, 16 waves/block -> 4 x 16 x 4 = 256 blocks
    // (1/CU, zero tail), (h,b)-clustered per XCD
    attn64<<<dim3(4, 16, 4), 1024, 0, stream>>>(Qp, Kp, Vp, packT, heads);
    // final: 128x64 tiles -> 32 x 16 = 512 blocks, XCD m-stripes,
    // counted-vmcnt 2-deep pipeline
    gemm_k<128, 64, 1, 4><<<dim3(32, 16, 1), 256, 0, stream>>>(
        heads, nullptr, nullptr, nullptr, WoT, bo, d_out,
        (const unsigned int*)d_in[0]);
}

// Round 9
// 219.227 us; speedup vs baseline: 1.0277x; 1.0240x over previous
//
#include <hip/hip_runtime.h>

// Problem constants (B,S,D,H,HD) = (4,1024,1024,16,64)
#define B_ 4
#define S_ 1024
#define D_ 1024
#define H_ 16
#define E_ 64
#define BS_ (B_*S_)
#define BHSE_ (B_*H_*S_*E_)   // 4,194,304

typedef __attribute__((ext_vector_type(8))) short bf16x8;   // 8 bf16 in 4 VGPRs
typedef __attribute__((ext_vector_type(4))) float f32x4;
typedef __attribute__((ext_vector_type(4))) unsigned int u32x4;

__device__ __forceinline__ unsigned short f2bf(float f) {
    unsigned int x = __float_as_uint(f);
    x = (x + 0x7FFFu + ((x >> 16) & 1u)) >> 16;   // RNE
    return (unsigned short)x;
}
__device__ __forceinline__ float bf2f(unsigned short u) {
    return __uint_as_float(((unsigned int)u) << 16);
}
__device__ __forceinline__ float ldin(const void* p, size_t i, int isb) {
    return isb ? bf2f(((const unsigned short*)p)[i]) : ((const float*)p)[i];
}

// 2 f32 -> packed 2xbf16 in one VALU op (RNE) — no builtin on gfx950, asm it
__device__ __forceinline__ unsigned int cvtpk(float lo, float hi) {
    unsigned int r;
    asm("v_cvt_pk_bf16_f32 %0, %1, %2" : "=v"(r) : "v"(lo), "v"(hi));
    return r;
}
__device__ __forceinline__ unsigned int bperm(int srclane4, unsigned int v) {
    return (unsigned int)__builtin_amdgcn_ds_bpermute(srclane4, (int)v);
}
__device__ __forceinline__ bf16x8 u4bf(u32x4 w) {
    union { u32x4 u; bf16x8 h; } c; c.u = w; return c.h;
}

// 2^x : v_exp_f32 is natively base-2
#if __has_builtin(__builtin_amdgcn_exp2f)
#define EXP2(x) __builtin_amdgcn_exp2f(x)
#else
#define EXP2(x) __expf((x) * 0.6931471805599453f)
#endif

// async global->LDS, 16B per lane; LDS dest = wave-uniform base + lane*16
__device__ __forceinline__ void gl2lds16(const void* g, void* l) {
    __builtin_amdgcn_global_load_lds(
        (const __attribute__((address_space(1))) void*)g,
        (__attribute__((address_space(3))) void*)l, 16, 0, 0);
}

// ---------------------------------------------------------------------------
// Per-block dtype self-detect. One 64-word coalesced read of q + one wave
// ballot; all waves compute the identical answer. Threshold 48/64.
// ---------------------------------------------------------------------------
__device__ __forceinline__ int detect_isb(const unsigned int* q) {
    unsigned int wv = q[threadIdx.x & 63];
    unsigned int lo = wv & 0xFFFFu;
    unsigned int e = (lo >> 7) & 0xFFu;
    int ok = (lo == 0u) || (e >= 100u && e <= 145u);
    return __popcll(__ballot(ok)) >= 48;
}

// ---------------------------------------------------------------------------
// Kernel 1: merged preprocessing — weights permute, mask bitpack, A convert.
// blocks [0,1024):     W{q,k,v}[h][d][e] -> WT[z][(h*64+e)][d]; Wo[d][o]->WT[3][o][d]
// blocks [1024,5120):  packT[b][kt][s] bit k = mask[b][s][kt*64+k]
// blocks [5120,11264): q,k,v fp32->bf16 one-shot convert (skip if bf16)
// ---------------------------------------------------------------------------
__global__ __launch_bounds__(256) void preproc(
        const void* q_, const void* k_, const void* v_, const int* mask,
        const void* Wq, const void* Wk, const void* Wv, const void* Wo,
        const void* bq_, const void* bk_, const void* bv_, const void* bo_,
        unsigned short* WT, float* biases, unsigned long long* packT,
        unsigned short* Aconv) {
    __shared__ unsigned short Tt[64][72];
    const int isb = detect_isb((const unsigned int*)q_);
    const int blk = blockIdx.x, t = threadIdx.x;

    if (blk < 1024) {
        // ---- weight permute ----
        const int c0 = blk & 15, r0 = ((blk >> 4) & 15) * 64, z = blk >> 8;
        const void* src = (z == 0) ? Wq : (z == 1) ? Wk : (z == 2) ? Wv : Wo;
        {
            int dl = t >> 2, qc = t & 3;
            size_t base;
            if (z < 3) base = (size_t)c0 * 65536 + (size_t)(r0 + dl) * 64 + qc * 16;
            else       base = (size_t)(r0 + dl) * 1024 + (size_t)c0 * 64 + qc * 16;
            if (isb) {
                const unsigned short* s = (const unsigned short*)src + base;
                bf16x8 a0 = *(const bf16x8*)s, a1 = *(const bf16x8*)(s + 8);
#pragma unroll
                for (int j = 0; j < 8; j++) {
                    Tt[qc * 16 + j][dl] = (unsigned short)a0[j];
                    Tt[qc * 16 + 8 + j][dl] = (unsigned short)a1[j];
                }
            } else {
                const float* s = (const float*)src + base;
#pragma unroll
                for (int j = 0; j < 16; j++) Tt[qc * 16 + j][dl] = f2bf(s[j]);
            }
        }
        __syncthreads();
        {
            int el = t >> 2, qc = t & 3;
            size_t dst = (size_t)z * D_ * D_ + (size_t)(c0 * 64 + el) * D_ + r0 + qc * 16;
            *(bf16x8*)&WT[dst]     = *(const bf16x8*)&Tt[el][qc * 16];
            *(bf16x8*)&WT[dst + 8] = *(const bf16x8*)&Tt[el][qc * 16 + 8];
        }
        if (z == 3 && ((blk >> 4) & 15) == 0 && c0 < 4) {
            const void* bs = (c0 == 0) ? bq_ : (c0 == 1) ? bk_
                           : (c0 == 2) ? bv_ : bo_;
#pragma unroll
            for (int j = 0; j < 4; j++) {
                int i = t * 4 + j;
                biases[c0 * 1024 + i] = ldin(bs, i, isb);
            }
        }
    } else if (blk < 5120) {
        // ---- mask bitpack: unit = (b, kt, 4 s-rows) per wave ----
        int unit = (blk - 1024) * 4 + (t >> 6);
        int lane = t & 63;
        int b = unit >> 12, rem = unit & 4095, s0 = (rem >> 4) * 4, kt = rem & 15;
        const int* mb = mask + ((size_t)b * 1024 + s0) * 1024 + kt * 64 + lane;
        unsigned long long bits[4];
#pragma unroll
        for (int j = 0; j < 4; j++) bits[j] = __ballot(mb[j * 1024] != 0);
        if (lane < 4) {
            unsigned long long bb = (lane == 0) ? bits[0] : (lane == 1) ? bits[1]
                                  : (lane == 2) ? bits[2] : bits[3];
            packT[((size_t)b * 16 + kt) * 1024 + s0 + lane] = bb;
        }
    } else {
        // ---- q,k,v fp32 -> bf16 ----
        if (isb) return;
        int blk2 = blk - 5120;
        const int z = blk2 >> 11;
        const float* s = (z == 0) ? (const float*)q_ : (z == 1) ? (const float*)k_
                                                                : (const float*)v_;
        const size_t i = ((size_t)(blk2 & 2047) * 256 + t) * 8;
        f32x4 a0 = *(const f32x4*)(s + i);
        f32x4 a1 = *(const f32x4*)(s + i + 4);
        bf16x8 o;
#pragma unroll
        for (int j = 0; j < 4; j++) {
            o[j]     = (short)f2bf(a0[j]);
            o[4 + j] = (short)f2bf(a1[j]);
        }
        *(bf16x8*)&Aconv[(size_t)z * ((size_t)BS_ * D_) + i] = o;
    }
}

// ---------------------------------------------------------------------------
// Kernel 3: bf16 MFMA GEMM — unchanged from R16 (counted-vmcnt 2-deep
// pipeline, 3 LDS buffers, XOR-4 swizzle, XCD m-stripes).
// MODE 0: proj, 128x128 tiles, grid (32,8,3).
// MODE 1: final GEMM, 128x64 tiles, grid (32,16).
// ---------------------------------------------------------------------------
template<int BM, int BN, int MODE, int MINW>
__global__ __launch_bounds__(256, MINW) void gemm_k(
        const void* A0, const void* A1, const void* A2, const unsigned short* Aconv,
        const unsigned short* BtB, const float* biasB, void* dstB,
        const unsigned int* qdet) {
    constexpr int TOT16 = (BM + BN) * 32;       // ushorts per buffer
    constexpr int CALLS = TOT16 / 512;          // 1KB chunks (16 rows x 32 cols)
    constexpr int CPW = CALLS / 4;              // DMA issues per wave per tile
    constexpr int MT = BM / 32;                 // wave-tile (BM/2)x(BN/2)
    constexpr int NT = BN / 32;
    __shared__ unsigned short buf[3][TOT16];

    const int fl = detect_isb(qdet);
    const int t = threadIdx.x, lane = t & 63, w = t >> 6;
    const int lm = lane & 15, q4 = lane >> 4;
    const int wm = w >> 1, wn = w & 1;
    const int lr = lane >> 2;                    // row-in-chunk 0..15
    const int ls = lane & 3;                     // LDS slot 0..3
    const int lg = ls ^ ((lr >> 1) & 3);         // source granule (swizzle)

    const unsigned short* Abf;
    const unsigned short* Bt;
    const float* bias;
    int z = 0, m0, n0, phase;
    if (MODE == 0) {
        // grid (32,8,3); dispatch id -> XCD = id & 7 (round-robin)
        int bid = blockIdx.x + gridDim.x * (blockIdx.y + gridDim.y * blockIdx.z);
        int xcd = bid & 7, idx = bid >> 3;       // idx 0..95 within XCD
        z = idx >> 5;                            // 0..2 (sequential per XCD)
        int r = idx & 31;
        int mt = (xcd << 2) + (r & 3);           // XCD x owns m-tiles 4x..4x+3
        int nt = r >> 2;                         // 0..7
        m0 = mt * BM; n0 = nt * BN;
        phase = (nt * 13 + z * 5) & 31;          // same-B blocks K-aligned
        const void* Ain = (z == 0) ? A0 : (z == 1 ? A1 : A2);
        Abf = fl ? (const unsigned short*)Ain
                 : Aconv + (size_t)z * ((size_t)BS_ * D_);
        Bt = BtB + (size_t)z * D_ * D_;
        bias = biasB + z * 1024;
    } else {
        Abf = (const unsigned short*)A0;         // heads, always bf16
        Bt = BtB; bias = biasB;
        // grid (32,16): 512 blocks; xcd owns m-tiles [4x,4x+4) x all 16 nt
        int bid = blockIdx.x + (blockIdx.y << 5);
        int xcd = bid & 7, idx = bid >> 3;       // idx 0..63
        m0 = ((xcd << 2) + (idx & 3)) * BM;
        n0 = (idx >> 2) * BN;
        phase = ((idx >> 2) * 13) & 31;
    }

    // stage K-slice kk into buffer bi (swizzled: slot s of row r holds
    // global granule s ^ ((r>>1)&3)) — pure DMA, A and B both bf16
    auto stage = [&](int kk, int bi) {
#pragma unroll
        for (int i = 0; i < CPW; ++i) {
            int c = w * CPW + i;
            int row = c * 16 + lr;
            const unsigned short* g;
            if (row < BM)
                g = Abf + (size_t)(m0 + row) * D_ + kk + lg * 8;
            else
                g = Bt + (size_t)(n0 + row - BM) * D_ + kk + lg * 8;
            gl2lds16(g, &buf[bi][c * 512]);
        }
    };

    f32x4 acc[MT][NT];
#pragma unroll
    for (int i = 0; i < MT; i++)
#pragma unroll
        for (int j = 0; j < NT; j++) acc[i][j] = (f32x4){0.f, 0.f, 0.f, 0.f};

    // prologue: 2 tiles in flight
    stage((phase & 31) * 32, 0);
    stage(((1 + phase) & 31) * 32, 1);
    for (int it = 0; it < D_ / 32; ++it) {
        const int bi = it % 3;
        // own tile-it loads done; newer tiles stay in flight across barrier
        if (it < D_ / 32 - 1) {
            asm volatile("s_waitcnt vmcnt(%0)" :: "n"(CPW) : "memory");
        } else {
            asm volatile("s_waitcnt vmcnt(0)" ::: "memory");
        }
        __builtin_amdgcn_s_barrier();
        __builtin_amdgcn_sched_barrier(0);
        if (it < D_ / 32 - 2) stage(((it + 2 + phase) & 31) * 32, (it + 2) % 3);

        const unsigned short* As = buf[bi];
        const unsigned short* Bs = buf[bi] + BM * 32;
        bf16x8 af[MT], bv[NT];
#pragma unroll
        for (int mt = 0; mt < MT; mt++) {
            int row = wm * (BM / 2) + mt * 16 + lm;
            af[mt] = *(const bf16x8*)&As[row * 32 + (q4 ^ ((row >> 1) & 3)) * 8];
        }
#pragma unroll
        for (int nt = 0; nt < NT; nt++) {
            int row = wn * (BN / 2) + nt * 16 + lm;
            bv[nt] = *(const bf16x8*)&Bs[row * 32 + (q4 ^ ((row >> 1) & 3)) * 8];
        }
#pragma unroll
        for (int mt = 0; mt < MT; mt++)
#pragma unroll
            for (int nt = 0; nt < NT; nt++)
                acc[mt][nt] = __builtin_amdgcn_mfma_f32_16x16x32_bf16(
                    af[mt], bv[nt], acc[mt][nt], 0, 0, 0);
    }

    // epilogue: C/D layout col=lane&15, row=(lane>>4)*4+reg
#pragma unroll
    for (int mt = 0; mt < MT; mt++)
#pragma unroll
        for (int nt = 0; nt < NT; nt++) {
            int N = n0 + wn * (BN / 2) + nt * 16 + lm;
            int Mb = m0 + wm * (BM / 2) + mt * 16 + q4 * 4;
            if (MODE == 0 && z == 2) {
                // V^T: 4 consecutive s per lane -> one b64 store
                int bb = Mb >> 10, sb = Mb & 1023, hh = N >> 6, e = N & 63;
                unsigned long long hv = 0;
#pragma unroll
                for (int r = 0; r < 4; r++)
                    hv |= (unsigned long long)f2bf(acc[mt][nt][r] + bias[N]) << (16 * r);
                unsigned short* d16 = (unsigned short*)dstB + (size_t)2 * BHSE_;
                *(unsigned long long*)&d16[(((size_t)(bb * H_ + hh) * E_ + e) << 10) + sb] = hv;
            } else {
#pragma unroll
                for (int r = 0; r < 4; r++) {
                    int M = Mb + r;
                    float v = acc[mt][nt][r] + bias[N];
                    if (MODE == 0) {
                        int bb = M >> 10, s = M & 1023, hh = N >> 6, e = N & 63;
                        unsigned short* d16 = (unsigned short*)dstB + (size_t)z * BHSE_;
                        d16[((size_t)(bb * H_ + hh) * S_ + s) * E_ + e] = f2bf(v);
                    } else {
                        size_t idx = (size_t)M * D_ + N;
                        if (fl) ((unsigned short*)dstB)[idx] = f2bf(v);
                        else    ((float*)dstB)[idx] = v;
                    }
                }
            }
        }
}

// ---------------------------------------------------------------------------
// Kernel 4 (R17): fused attention. CHANGED vs R16:
//  (1) KV stage granularity 128 -> 256 keys: LDS 64 -> 128 KB (free: grid
//      already pins 1 block/CU and 128 KB < 160 KB). Loop 4 iterations;
//      barriers / buffer swaps / stage syncs halve. Per-128-key processing
//      (QK/softmax/PV + registers) byte-identical, done as two halves per
//      staged tile.
//  (2) T5 s_setprio(1) around the QK and PV MFMA clusters: attn waves are
//      not lockstep within a tile (independent per-wave softmax) -> role
//      diversity exists; m191 measured +4-7% on attn.
// ---------------------------------------------------------------------------
__global__ __launch_bounds__(1024, 4) void attn64(
        const unsigned short* Qp, const unsigned short* Kp, const unsigned short* VpT,
        const unsigned long long* packT, unsigned short* heads) {
    __shared__ unsigned short KT[2][16384];  // [buf][256 keys x 64 e], swizzled
    __shared__ unsigned short VT[2][16384];  // [buf][4 sub][64 e x 64 keys], swz

    // XCD remap: grid (4,16,4): bid = qt + 4*(h + 16*b); hw xcd = bid&7.
    // Give each xcd 8 full hb's: hb = xcd*8 + (idx&7), qt = idx>>3 (0..3).
    const int bid = blockIdx.x + (blockIdx.y << 2) + (blockIdx.z << 6);
    const int xcd = bid & 7, idx = bid >> 3;
    const int qt = idx >> 3;
    const int hb = xcd * 8 + (idx & 7);
    const int h = hb & 15, b = hb >> 4;

    const int t = threadIdx.x, w = t >> 6, lane = t & 63, lm = lane & 15, q4 = lane >> 4;
    const size_t bh = ((size_t)b * H_ + h) * S_ * E_;
    const unsigned short* Qb = Qp + bh;
    const unsigned short* Kb = Kp + bh;
    const unsigned short* Vb = VpT + bh;                // Vb[e*1024 + s]
    const int q0 = qt * 256 + w * 16;

    // per-lane invariant DMA source offsets (ushort units)
    const int l3 = lane >> 3, l7 = lane & 7;
    const int kLaneOff = l3 * 64 + (l7 ^ l3) * 8;       // within an 8-row K chunk
    const int vLaneOff = l3 * 1024 + (l7 ^ l3) * 8;     // within an 8-row V chunk

    // swizzled LDS fragment chunk indices (granule = 8 ushorts)
    const int sw = lm & 7;
    const int c0 = (q4 ^ sw) * 8, c1 = ((q4 ^ 4) ^ sw) * 8;

    // bpermute source byte-addresses for the P redistribution
    const int srcA4 = ((lane & 15) | ((lane & 16) << 1)) << 2;  // (lm+(q4&1)*32)*4
    const int srcB4 = srcA4 + 64;                               // +16 lanes
    const bool selHi = (lane & 32) != 0;                        // q4 >= 2

    // Q B-fragments, held for the whole sweep
    bf16x8 bq0 = *(const bf16x8*)&Qb[(size_t)(q0 + lm) * E_ + q4 * 8];
    bf16x8 bq1 = *(const bf16x8*)&Qb[(size_t)(q0 + lm) * E_ + 32 + q4 * 8];

    // all-ones A-fragment for the denominator MFMA
    bf16x8 ones;
#pragma unroll
    for (int j = 0; j < 8; j++) ones[j] = (short)0x3F80;

    f32x4 oacc[4];
#pragma unroll
    for (int i = 0; i < 4; i++) oacc[i] = (f32x4){0.f, 0.f, 0.f, 0.f};
    f32x4 accL = (f32x4){0.f, 0.f, 0.f, 0.f};
    float mrun = -3.0e38f;
    const float scale2 = 0.03125f * 1.4426950408889634f;   // log2e / sqrt(D)

// 256-key tile = 64 x 1KB chunks over 16 waves: 4 DMA issues/wave/tile.
// K chunks 0..31: rows c*8..c*8+7 of [256 keys][64 e].
// V chunks 32..63: cc=c-32, sub=cc>>3 (64-key group), ec=cc&7 (e-rows ec*8).
#define STAGE(tile, bufi)                                                     \
    {                                                                         \
        int k0s = (tile) * 256;                                               \
        _Pragma("unroll")                                                     \
        for (int i_ = 0; i_ < 4; ++i_) {                                      \
            int c_ = w * 4 + i_;                                              \
            if (c_ < 32) {                                                    \
                gl2lds16(Kb + (size_t)k0s * 64 + c_ * 512 + kLaneOff,         \
                         &KT[bufi][c_ * 512]);                                \
            } else {                                                          \
                int cc_ = c_ - 32, sub_ = cc_ >> 3, ec_ = cc_ & 7;            \
                gl2lds16(Vb + (size_t)ec_ * 8192 + k0s + sub_ * 64 + vLaneOff,\
                         &VT[bufi][sub_ * 4096 + ec_ * 512]);                 \
            }                                                                 \
        }                                                                     \
    }

    STAGE(0, 0)
    unsigned long long mk[4], mkn[4];
#pragma unroll
    for (int j = 0; j < 4; j++)
        mk[j] = packT[((size_t)b * 16 + j) * 1024 + q0 + lm];

    for (int T = 0; T < S_ / 256; ++T) {
        const int bufi = T & 1;
        __syncthreads();                 // own-vmcnt drain + barrier: tile T ready
        if (T < 3) {
            STAGE(T + 1, bufi ^ 1)
#pragma unroll
            for (int j = 0; j < 4; j++)
                mkn[j] = packT[((size_t)b * 16 + 4 * T + 4 + j) * 1024 + q0 + lm];
        }

#pragma unroll
        for (int half = 0; half < 2; ++half) {
            // Sc^T for both 64-key sub-tiles of this half (16 MFMAs)
            f32x4 st[2][4];
            __builtin_amdgcn_s_setprio(1);
#pragma unroll
            for (int sub = 0; sub < 2; ++sub)
#pragma unroll
                for (int jt = 0; jt < 4; ++jt) {
                    const unsigned short* kr =
                        &KT[bufi][(half * 128 + sub * 64 + jt * 16 + lm) * 64];
                    bf16x8 ka0 = *(const bf16x8*)&kr[c0];
                    bf16x8 ka1 = *(const bf16x8*)&kr[c1];
                    f32x4 zz = (f32x4){0.f, 0.f, 0.f, 0.f};
                    zz = __builtin_amdgcn_mfma_f32_16x16x32_bf16(ka0, bq0, zz, 0, 0, 0);
                    zz = __builtin_amdgcn_mfma_f32_16x16x32_bf16(ka1, bq1, zz, 0, 0, 0);
                    st[sub][jt] = zz;
                }
            __builtin_amdgcn_s_setprio(0);

            // per-lane PARTIAL row max over this lane's 32 raw scores
            float tmx = -3.0e38f;
#pragma unroll
            for (int sub = 0; sub < 2; ++sub)
#pragma unroll
                for (int jt = 0; jt < 4; ++jt) {
                    float a = fmaxf(st[sub][jt][0], st[sub][jt][1]);
                    float c = fmaxf(st[sub][jt][2], st[sub][jt][3]);
                    tmx = fmaxf(tmx, fmaxf(a, c));
                }
            float pmax = tmx * scale2;   // per-lane partial scaled tile max

            // defer-max: __all on partials covers all (q,k); full row-max
            // reduction only inside the rarely-taken branch.
            if (!__all(pmax - mrun <= 8.f)) {
                float rmx = pmax;
                rmx = fmaxf(rmx, __shfl_xor(rmx, 16, 64));
                rmx = fmaxf(rmx, __shfl_xor(rmx, 32, 64));   // true row max
                float mnew = fmaxf(mrun, rmx);
                float alpha = EXP2(mrun - mnew);
                accL = accL * alpha;
#pragma unroll
                for (int nt = 0; nt < 4; nt++) oacc[nt] = oacc[nt] * alpha;
                mrun = mnew;
            }
            const float mneg = -mrun;

            // exp + mask + pack, both subs
            unsigned int cl[2][8];
#pragma unroll
            for (int sub = 0; sub < 2; ++sub) {
                unsigned long long mkv = mk[half * 2 + sub];
                unsigned int mn = (unsigned int)(mkv >> (q4 * 4));
                unsigned int mh = (unsigned int)(mkv >> (q4 * 4 + 32));
#pragma unroll
                for (int jt = 0; jt < 4; ++jt) {
                    unsigned int mm = (jt & 2) ? mh : mn;
                    const int sh = (jt & 1) * 16;
                    float p0 = EXP2(fmaf(st[sub][jt][0], scale2, mneg));
                    float p1 = EXP2(fmaf(st[sub][jt][1], scale2, mneg));
                    float p2 = EXP2(fmaf(st[sub][jt][2], scale2, mneg));
                    float p3 = EXP2(fmaf(st[sub][jt][3], scale2, mneg));
                    p0 = (mm & (1u << (sh + 0))) ? p0 : 0.f;
                    p1 = (mm & (1u << (sh + 1))) ? p1 : 0.f;
                    p2 = (mm & (1u << (sh + 2))) ? p2 : 0.f;
                    p3 = (mm & (1u << (sh + 3))) ? p3 : 0.f;
                    cl[sub][jt * 2]     = cvtpk(p0, p1);
                    cl[sub][jt * 2 + 1] = cvtpk(p2, p3);
                }
            }

            // in-register C->B redistribution per sub, then denom + PV MFMAs
#pragma unroll
            for (int sub = 0; sub < 2; ++sub) {
                unsigned int* c = cl[sub];
                u32x4 w0, w1;
                {
                    unsigned int aA0 = bperm(srcA4, c[0]), aA2 = bperm(srcA4, c[2]);
                    unsigned int aA1 = bperm(srcA4, c[1]), aA3 = bperm(srcA4, c[3]);
                    unsigned int aB0 = bperm(srcB4, c[0]), aB2 = bperm(srcB4, c[2]);
                    unsigned int aB1 = bperm(srcB4, c[1]), aB3 = bperm(srcB4, c[3]);
                    w0 = (u32x4){selHi ? aA2 : aA0, selHi ? aA3 : aA1,
                                 selHi ? aB2 : aB0, selHi ? aB3 : aB1};
                    unsigned int bA0 = bperm(srcA4, c[4]), bA2 = bperm(srcA4, c[6]);
                    unsigned int bA1 = bperm(srcA4, c[5]), bA3 = bperm(srcA4, c[7]);
                    unsigned int bB0 = bperm(srcB4, c[4]), bB2 = bperm(srcB4, c[6]);
                    unsigned int bB1 = bperm(srcB4, c[5]), bB3 = bperm(srcB4, c[7]);
                    w1 = (u32x4){selHi ? bA2 : bA0, selHi ? bA3 : bA1,
                                 selHi ? bB2 : bB0, selHi ? bB3 : bB1};
                }
                bf16x8 bp0 = u4bf(w0);
                bf16x8 bp1 = u4bf(w1);

                __builtin_amdgcn_s_setprio(1);
                // denominator via ones-MFMA (rows of D = col-sums of B)
                accL = __builtin_amdgcn_mfma_f32_16x16x32_bf16(ones, bp0, accL, 0, 0, 0);
                accL = __builtin_amdgcn_mfma_f32_16x16x32_bf16(ones, bp1, accL, 0, 0, 0);

                // PV from this sub's V block
                const unsigned short* vbase = &VT[bufi][(half * 2 + sub) * 4096];
#pragma unroll
                for (int nt = 0; nt < 4; nt++) {
                    const unsigned short* vr = &vbase[(nt * 16 + lm) * 64];
                    bf16x8 va0 = *(const bf16x8*)&vr[c0];
                    bf16x8 va1 = *(const bf16x8*)&vr[c1];
                    oacc[nt] = __builtin_amdgcn_mfma_f32_16x16x32_bf16(va0, bp0, oacc[nt], 0, 0, 0);
                    oacc[nt] = __builtin_amdgcn_mfma_f32_16x16x32_bf16(va1, bp1, oacc[nt], 0, 0, 0);
                }
                __builtin_amdgcn_s_setprio(0);
            }
        }

#pragma unroll
        for (int j = 0; j < 4; j++) mk[j] = mkn[j];
    }

    float inv = 1.0f / accL[0];
#pragma unroll
    for (int nt = 0; nt < 4; nt++) {
        unsigned int lo = cvtpk(oacc[nt][0] * inv, oacc[nt][1] * inv);
        unsigned int hi = cvtpk(oacc[nt][2] * inv, oacc[nt][3] * inv);
        unsigned long long hv = (unsigned long long)lo | ((unsigned long long)hi << 32);
        *(unsigned long long*)&heads[(size_t)(b * S_ + q0 + lm) * D_ + h * E_ + nt * 16 + q4 * 4] = hv;
    }
}

// ---------------------------------------------------------------------------
extern "C" void kernel_launch(void* const* d_in, const int* in_sizes, int n_in,
                              void* d_out, int out_size, void* d_ws, size_t ws_size,
                              hipStream_t stream) {
    char* ws = (char*)d_ws;
    unsigned short* WT = (unsigned short*)(ws + 256);    // [4][1024][1024] bf16
    unsigned short* WqT = WT;
    unsigned short* WoT = WT + (size_t)3 * D_ * D_;
    float* biases = (float*)(WT + (size_t)4 * D_ * D_);  // [4][1024]
    float* bq = biases;
    float* bo = biases + 3 * 1024;
    unsigned short* Qp = (unsigned short*)(biases + 4 * 1024);  // [b][h][s][e]
    unsigned short* Kp = Qp + (size_t)BHSE_;                    // [b][h][s][e]
    unsigned short* Vp = Kp + (size_t)BHSE_;                    // [b][h][e][s]
    unsigned short* heads = Vp + (size_t)BHSE_;                 // [b*s][h*64+e]
    unsigned long long* packT = (unsigned long long*)(heads + (size_t)BHSE_);
    unsigned short* Aconv = (unsigned short*)(packT + (size_t)B_ * 16 * S_); // [3][4096][1024] bf16

    // merged preprocessing: weights + bias, mask bitpack, A fp32->bf16
    preproc<<<11264, 256, 0, stream>>>(
        d_in[0], d_in[1], d_in[2], (const int*)d_in[3],
        d_in[4], d_in[6], d_in[8], d_in[10],
        d_in[5], d_in[7], d_in[9], d_in[11],
        WT, biases, packT, Aconv);
    // proj: 128x128 tiles -> 32 x 8 x 3 = 768 blocks (3/CU), XCD m-stripes,
    // counted-vmcnt 2-deep pipeline
    gemm_k<128, 128, 0, 3><<<dim3(32, 8, 3), 256, 0, stream>>>(
        d_in[0], d_in[1], d_in[2], Aconv, WqT, bq, Qp,
        (const unsigned int*)d_in[0]);
    // attn: QBLK=256 x KVSTAGE=256, 16 waves/block -> 4 x 16 x 4 = 256 blocks
    // (1/CU, zero tail), (h,b)-clustered per XCD, setprio on MFMA clusters
    attn64<<<dim3(4, 16, 4), 1024, 0, stream>>>(Qp, Kp, Vp, packT, heads);
    // final: 128x64 tiles -> 32 x 16 = 512 blocks, XCD m-stripes,
    // counted-vmcnt 2-deep pipeline
    gemm_k<128, 64, 1, 4><<<dim3(32, 16, 1), 256, 0, stream>>>(
        heads, nullptr, nullptr, nullptr, WoT, bo, d_out,
        (const unsigned int*)d_in[0]);
}